// Round 1
// baseline (86.710 us; speedup 1.0000x reference)
//
#include <hip/hip_runtime.h>
#include <hip/hip_bf16.h>

#define N_ROWS 10000
#define F_DIM 256
#define J4 (N_ROWS / 4)   // 2500 float4 per row

// Kernel 1: per-row dot products. One 256-thread block per row.
// s1b[i] = dot(x[i], w1) + b;  s2[i] = dot(x[i], w2)
__global__ void dot_kernel(const float* __restrict__ x,
                           const float* __restrict__ w,
                           const float* __restrict__ b,
                           float* __restrict__ s1b,
                           float* __restrict__ s2) {
    const int row = blockIdx.x;
    const int t = threadIdx.x;          // 0..255
    const float xv = x[(size_t)row * F_DIM + t];
    float p1 = xv * w[t];
    float p2 = xv * w[F_DIM + t];
    // wave-64 butterfly reduce
    #pragma unroll
    for (int o = 32; o > 0; o >>= 1) {
        p1 += __shfl_down(p1, o);
        p2 += __shfl_down(p2, o);
    }
    __shared__ float a1[4], a2[4];
    const int wid = t >> 6;
    if ((t & 63) == 0) { a1[wid] = p1; a2[wid] = p2; }
    __syncthreads();
    if (t == 0) {
        s1b[row] = (a1[0] + a1[1] + a1[2] + a1[3]) + b[0];
        s2[row]  = (a2[0] + a2[1] + a2[2] + a2[3]);
    }
}

__device__ __forceinline__ float sigmoidf(float z) {
    return 1.0f / (1.0f + __expf(-z));
}

// Kernel 2: out[i][j] = sigmoid(s1b[i] + s2[j]).  float4 per thread.
__global__ void att_kernel(const float* __restrict__ s1b,
                           const float* __restrict__ s2,
                           float* __restrict__ out) {
    const int row = blockIdx.y;
    const int j4 = blockIdx.x * blockDim.x + threadIdx.x;
    if (j4 >= J4) return;
    const float a = s1b[row];
    float4 v = reinterpret_cast<const float4*>(s2)[j4];
    float4 r;
    r.x = sigmoidf(a + v.x);
    r.y = sigmoidf(a + v.y);
    r.z = sigmoidf(a + v.z);
    r.w = sigmoidf(a + v.w);
    reinterpret_cast<float4*>(out)[(size_t)row * J4 + j4] = r;
}

extern "C" void kernel_launch(void* const* d_in, const int* in_sizes, int n_in,
                              void* d_out, int out_size, void* d_ws, size_t ws_size,
                              hipStream_t stream) {
    const float* x = (const float*)d_in[0];
    // d_in[1] = adj (unused by the reference output)
    const float* w = (const float*)d_in[2];
    const float* b = (const float*)d_in[3];
    float* out = (float*)d_out;

    float* s1b = (float*)d_ws;              // N_ROWS floats
    float* s2  = s1b + N_ROWS;              // N_ROWS floats

    dot_kernel<<<N_ROWS, F_DIM, 0, stream>>>(x, w, b, s1b, s2);

    dim3 grid((J4 + 255) / 256, N_ROWS);
    att_kernel<<<grid, 256, 0, stream>>>(s1b, s2, out);
}

// Round 2
// 82.857 us; speedup vs baseline: 1.0465x; 1.0465x over previous
//
#include <hip/hip_runtime.h>
#include <hip/hip_bf16.h>

#define N_ROWS 10000
#define F_DIM 256
#define J4 (N_ROWS / 4)   // 2500 float4 per row
#define LOG2E 1.44269504088896340736f

typedef float f32x4 __attribute__((ext_vector_type(4)));

// Kernel 1: per-row dot products -> store e1[i] = exp(-(x@w1 + b)), e2[j] = exp(-(x@w2)).
// 4 waves per block, one row per wave, float4 loads (256 floats / 64 lanes = 1 float4 each).
__global__ void dot_kernel(const float* __restrict__ x,
                           const float* __restrict__ w,
                           const float* __restrict__ b,
                           float* __restrict__ e1,
                           float* __restrict__ e2) {
    const int wid  = threadIdx.x >> 6;          // wave 0..3
    const int lane = threadIdx.x & 63;
    const int row  = blockIdx.x * 4 + wid;
    const f32x4 xv = reinterpret_cast<const f32x4*>(x + (size_t)row * F_DIM)[lane];
    const f32x4 w1 = reinterpret_cast<const f32x4*>(w)[lane];
    const f32x4 w2 = reinterpret_cast<const f32x4*>(w + F_DIM)[lane];
    float p1 = xv.x * w1.x + xv.y * w1.y + xv.z * w1.z + xv.w * w1.w;
    float p2 = xv.x * w2.x + xv.y * w2.y + xv.z * w2.z + xv.w * w2.w;
    #pragma unroll
    for (int o = 32; o > 0; o >>= 1) {
        p1 += __shfl_xor(p1, o);
        p2 += __shfl_xor(p2, o);
    }
    if (lane == 0) {
        e1[row] = __builtin_amdgcn_exp2f(-(p1 + b[0]) * LOG2E);
        e2[row] = __builtin_amdgcn_exp2f(-p2 * LOG2E);
    }
}

// Kernel 2: out[i][j] = 1 / (1 + e1[i]*e2[j]).
// Each thread: one float4 of e2, 4 consecutive rows -> 4 nontemporal float4 stores.
__global__ void att_kernel(const float* __restrict__ e1,
                           const float* __restrict__ e2,
                           float* __restrict__ out) {
    const int j4 = blockIdx.x * blockDim.x + threadIdx.x;   // 0..J4-1
    if (j4 >= J4) return;
    const int i0 = blockIdx.y * 4;
    const f32x4 ev = reinterpret_cast<const f32x4*>(e2)[j4];
    #pragma unroll
    for (int r = 0; r < 4; ++r) {
        const float a = e1[i0 + r];
        f32x4 o;
        o.x = __builtin_amdgcn_rcpf(fmaf(a, ev.x, 1.0f));
        o.y = __builtin_amdgcn_rcpf(fmaf(a, ev.y, 1.0f));
        o.z = __builtin_amdgcn_rcpf(fmaf(a, ev.z, 1.0f));
        o.w = __builtin_amdgcn_rcpf(fmaf(a, ev.w, 1.0f));
        __builtin_nontemporal_store(
            o, reinterpret_cast<f32x4*>(out) + (size_t)(i0 + r) * J4 + j4);
    }
}

extern "C" void kernel_launch(void* const* d_in, const int* in_sizes, int n_in,
                              void* d_out, int out_size, void* d_ws, size_t ws_size,
                              hipStream_t stream) {
    const float* x = (const float*)d_in[0];
    // d_in[1] = adj (unused by the reference output)
    const float* w = (const float*)d_in[2];
    const float* b = (const float*)d_in[3];
    float* out = (float*)d_out;

    float* e1 = (float*)d_ws;               // N_ROWS floats
    float* e2 = e1 + N_ROWS;                // N_ROWS floats

    dot_kernel<<<N_ROWS / 4, 256, 0, stream>>>(x, w, b, e1, e2);

    dim3 grid((J4 + 255) / 256, N_ROWS / 4);
    att_kernel<<<grid, 256, 0, stream>>>(e1, e2, out);
}